// Round 9
// baseline (208.166 us; speedup 1.0000x reference)
//
#include <hip/hip_runtime.h>
#include <hip/hip_bf16.h>

#define NFFT 8192
#define NH   4096
#define D    1024
#define NSEQ 4096
#define NDP  512
#define BATCH 4
#define NT   512
#define TSLOT 4097
#define PI_D 3.14159265358979323846

// 16-pt DFT internal constants
#define C1 0.92387953251128675613f
#define S1 0.38268343236508977173f
#define RT 0.70710678118654752440f

__device__ __forceinline__ int SWZ(int i) { return i ^ ((i >> 4) & 15) ^ ((i >> 8) & 15); }

__device__ __forceinline__ float2 cadd(float2 a, float2 b){ return make_float2(a.x+b.x, a.y+b.y); }
__device__ __forceinline__ float2 csub(float2 a, float2 b){ return make_float2(a.x-b.x, a.y-b.y); }
__device__ __forceinline__ float2 cmul(float2 a, float2 w){ return make_float2(a.x*w.x - a.y*w.y, a.x*w.y + a.y*w.x); }
__device__ __forceinline__ float2 cmulc(float2 a, float2 w){ return make_float2(a.x*w.x + a.y*w.y, a.y*w.x - a.x*w.y); }

__global__ __launch_bounds__(256) void wtab_init(float2* __restrict__ wtab) {
    int m = blockIdx.x * 256 + threadIdx.x;   // grid 16 -> 4096 entries
    double a = -2.0 * PI_D * (double)m / (double)NFFT;
    wtab[m] = make_float2((float)cos(a), (float)sin(a));
}

// in-register 16-pt DFT (DIF layers), in-place on v[16]
template<bool INV>
__device__ __forceinline__ void dft16(float2 v[16]) {
    float2 s[4][4];
    #pragma unroll
    for (int i = 0; i < 4; ++i) {
        float2 z0=v[i], z1=v[i+4], z2=v[i+8], z3=v[i+12];
        float2 A=cadd(z0,z2), Cc=csub(z0,z2), B=cadd(z1,z3), Dd=csub(z1,z3);
        s[i][0] = cadd(A,B);
        s[i][2] = csub(A,B);
        if (!INV) { s[i][1] = make_float2(Cc.x+Dd.y, Cc.y-Dd.x);
                    s[i][3] = make_float2(Cc.x-Dd.y, Cc.y+Dd.x); }
        else      { s[i][1] = make_float2(Cc.x-Dd.y, Cc.y+Dd.x);
                    s[i][3] = make_float2(Cc.x+Dd.y, Cc.y-Dd.x); }
    }
    if (!INV) {
        s[1][1]=cmul(s[1][1],make_float2(C1,-S1)); s[1][2]=cmul(s[1][2],make_float2(RT,-RT)); s[1][3]=cmul(s[1][3],make_float2(S1,-C1));
        s[2][1]=cmul(s[2][1],make_float2(RT,-RT)); s[2][2]=make_float2(s[2][2].y,-s[2][2].x); s[2][3]=cmul(s[2][3],make_float2(-RT,-RT));
        s[3][1]=cmul(s[3][1],make_float2(S1,-C1)); s[3][2]=cmul(s[3][2],make_float2(-RT,-RT)); s[3][3]=cmul(s[3][3],make_float2(-C1,S1));
    } else {
        s[1][1]=cmul(s[1][1],make_float2(C1,S1));  s[1][2]=cmul(s[1][2],make_float2(RT,RT));  s[1][3]=cmul(s[1][3],make_float2(S1,C1));
        s[2][1]=cmul(s[2][1],make_float2(RT,RT));  s[2][2]=make_float2(-s[2][2].y,s[2][2].x); s[2][3]=cmul(s[2][3],make_float2(-RT,RT));
        s[3][1]=cmul(s[3][1],make_float2(S1,C1));  s[3][2]=cmul(s[3][2],make_float2(-RT,RT)); s[3][3]=cmul(s[3][3],make_float2(-C1,-S1));
    }
    #pragma unroll
    for (int o = 0; o < 4; ++o) {
        float2 z0=s[0][o], z1=s[1][o], z2=s[2][o], z3=s[3][o];
        float2 A=cadd(z0,z2), Cc=csub(z0,z2), B=cadd(z1,z3), Dd=csub(z1,z3);
        v[o]    = cadd(A,B);
        v[o+8]  = csub(A,B);
        if (!INV) { v[o+4]  = make_float2(Cc.x+Dd.y, Cc.y-Dd.x);
                    v[o+12] = make_float2(Cc.x-Dd.y, Cc.y+Dd.x); }
        else      { v[o+4]  = make_float2(Cc.x-Dd.y, Cc.y+Dd.x);
                    v[o+12] = make_float2(Cc.x+Dd.y, Cc.y-Dd.x); }
    }
}

__device__ __forceinline__ void twiddle_fwd(float2 v[16], const float2* __restrict__ wt, int tw1i) {
    float2 w1 = wt[tw1i];
    float2 w2 = cmul(w1,w1), w3 = cmul(w2,w1), w4 = cmul(w2,w2), w8 = cmul(w4,w4), w12 = cmul(w8,w4);
    v[1]=cmul(v[1],w1);  v[2]=cmul(v[2],w2);  v[3]=cmul(v[3],w3);
    v[4]=cmul(v[4],w4);  v[5]=cmul(v[5],cmul(w4,w1));  v[6]=cmul(v[6],cmul(w4,w2));  v[7]=cmul(v[7],cmul(w4,w3));
    v[8]=cmul(v[8],w8);  v[9]=cmul(v[9],cmul(w8,w1));  v[10]=cmul(v[10],cmul(w8,w2)); v[11]=cmul(v[11],cmul(w8,w3));
    v[12]=cmul(v[12],w12); v[13]=cmul(v[13],cmul(w12,w1)); v[14]=cmul(v[14],cmul(w12,w2)); v[15]=cmul(v[15],cmul(w12,w3));
}
__device__ __forceinline__ void twiddle_inv(float2 v[16], const float2* __restrict__ wt, int tw1i) {
    float2 w1 = wt[tw1i];
    float2 w2 = cmul(w1,w1), w3 = cmul(w2,w1), w4 = cmul(w2,w2), w8 = cmul(w4,w4), w12 = cmul(w8,w4);
    v[1]=cmulc(v[1],w1);  v[2]=cmulc(v[2],w2);  v[3]=cmulc(v[3],w3);
    v[4]=cmulc(v[4],w4);  v[5]=cmulc(v[5],cmul(w4,w1));  v[6]=cmulc(v[6],cmul(w4,w2));  v[7]=cmulc(v[7],cmul(w4,w3));
    v[8]=cmulc(v[8],w8);  v[9]=cmulc(v[9],cmul(w8,w1));  v[10]=cmulc(v[10],cmul(w8,w2)); v[11]=cmulc(v[11],cmul(w8,w3));
    v[12]=cmulc(v[12],w12); v[13]=cmulc(v[13],cmul(w12,w1)); v[14]=cmulc(v[14],cmul(w12,w2)); v[15]=cmulc(v[15],cmul(w12,w3));
}

// middle pass (H=16) over LDS, unchanged structure
template<bool INV>
__device__ __forceinline__ void pass16mid(float2* zs, const float2* __restrict__ wt, int t) {
    int blk = t >> 8;
    int g = (t >> 4) & 15, j = t & 15;
    int i0 = blk*4096 + g*256 + j;
    int tw1i = 32*j;
    float2 v[16];
    #pragma unroll
    for (int q = 0; q < 16; ++q) v[q] = zs[SWZ(i0 + 16*q)];
    if (INV) twiddle_inv(v, wt, tw1i);
    dft16<INV>(v);
    if (!INV) twiddle_fwd(v, wt, tw1i);
    #pragma unroll
    for (int r = 0; r < 16; ++r) zs[SWZ(i0 + 16*r)] = v[r];
}

// chunk-pair helper: position bits [12]=b0,[11:8]=d1,[7:4]=d2,[3:0]=q; k = b0+2*d1+32*d2+512*q
__device__ __forceinline__ void pair_chunk(int b0, int d1, int d2,
                                           int& pbase, int& br2, int& kbase) {
    int nd1, nd2;
    if (b0 == 0) {
        int br1 = (d1 != 0);
        nd1 = (16 - d1) & 15;
        nd2 = (16 - d2 - br1) & 15;
        br2 = ((d2 != 0) || br1) ? 1 : 0;
    } else {
        nd1 = 15 - d1; nd2 = 15 - d2; br2 = 1;
    }
    pbase = (((b0 << 8) | (nd1 << 4) | nd2) << 4);
    kbase = b0 + 2*d1 + 32*d2;
}

// ---------- tspec: fwd FFT of packed t-pair, untangle -> store (T0,T1) at slot kr ----------
template<int PACKED>
__global__ __launch_bounds__(NT, 2) void tspec_kernel(const float2* __restrict__ tP,
                                                      const float* __restrict__ tg,
                                                      const float2* __restrict__ wt,
                                                      float4* __restrict__ tspecU) {
    __shared__ float2 zs[NFFT];
    int t = threadIdx.x, dp = blockIdx.x;
    int blk = t >> 8, j = t & 255;
    float2 v[16];

    // A: load + first radix-2 + P256(fwd) in regs
    #pragma unroll
    for (int q = 0; q < 16; ++q) {
        int n = j + (q << 8);
        float2 a, c;
        if (PACKED) { const float2* s_ = tP + (size_t)dp * NFFT; a = s_[n]; c = s_[n + NH]; }
        else { const float* tb = tg + 2*dp; a = *(const float2*)(tb + (size_t)n*D); c = *(const float2*)(tb + (size_t)(n+NH)*D); }
        v[q] = blk ? cmul(csub(a, c), wt[n]) : cadd(a, c);
    }
    dft16<false>(v);
    twiddle_fwd(v, wt, 2*j);
    #pragma unroll
    for (int r = 0; r < 16; ++r) zs[SWZ((blk<<12) + j + (r<<8))] = v[r];
    __syncthreads();

    pass16mid<false>(zs, wt, t);
    __syncthreads();

    // C: P1(fwd) in regs, publish, untangle -> store T
    int b0 = blk, d1 = t & 15, d2 = (t >> 4) & 15;
    int i0 = (((b0 << 8) | (d1 << 4) | d2) << 4);
    #pragma unroll
    for (int q = 0; q < 16; ++q) v[q] = zs[SWZ(i0 + q)];
    dft16<false>(v);
    #pragma unroll
    for (int q = 0; q < 16; ++q) zs[SWZ(i0 + q)] = v[q];
    __syncthreads();

    int pbase, br2, kbase;
    pair_chunk(b0, d1, d2, pbase, br2, kbase);
    float4* o = tspecU + (size_t)dp * TSLOT;
    #pragma unroll
    for (int q = 0; q < 16; ++q) {
        int k = kbase + (q << 9);
        bool lo = (q < 8) || (k <= 4096);
        if (lo) {
            int qp = (16 - q - br2) & 15;
            float2 z1 = v[q];
            float2 z2 = zs[SWZ(pbase + qp)];
            o[k] = make_float4(0.5f*(z1.x + z2.x), 0.5f*(z1.y - z2.y),
                               0.5f*(z1.y + z2.y), 0.5f*(z2.x - z1.x));
        }
    }
}

// ---------- conv: grid (NDP, BATCH) ----------
template<int PACKED>
__global__ __launch_bounds__(NT, 2) void conv_kernel(float2* __restrict__ xP,
                                                     const float* __restrict__ xg,
                                                     float* __restrict__ outg,
                                                     const float2* __restrict__ wt,
                                                     const float4* __restrict__ tspecU) {
    __shared__ float2 zs[NFFT];
    int t = threadIdx.x;
    int dp = blockIdx.x, b = blockIdx.y;
    int blk = t >> 8, j = t & 255;
    float2 v[16];
    float2* slab = PACKED ? (xP + ((size_t)dp * BATCH + b) * NSEQ) : nullptr;
    const float* xb = PACKED ? nullptr : (xg + (size_t)b * NSEQ * D + 2 * dp);

    // ---- A: load + first radix-2 (zero-padded) + P256(fwd) in regs ----
    #pragma unroll
    for (int q = 0; q < 16; ++q) {
        int n = j + (q << 8);
        float2 xv = PACKED ? slab[n] : *(const float2*)(xb + (size_t)n * D);
        v[q] = blk ? cmul(xv, wt[n]) : xv;
    }
    dft16<false>(v);
    twiddle_fwd(v, wt, 2*j);
    #pragma unroll
    for (int r = 0; r < 16; ++r) zs[SWZ((blk<<12) + j + (r<<8))] = v[r];
    __syncthreads();

    pass16mid<false>(zs, wt, t);
    __syncthreads();

    // ---- C: P1(fwd) + untangle*T + P1(inv), one LDS exchange ----
    int b0 = blk, d1 = t & 15, d2 = (t >> 4) & 15;
    int i0 = (((b0 << 8) | (d1 << 4) | d2) << 4);
    #pragma unroll
    for (int q = 0; q < 16; ++q) v[q] = zs[SWZ(i0 + q)];
    dft16<false>(v);
    #pragma unroll
    for (int q = 0; q < 16; ++q) zs[SWZ(i0 + q)] = v[q];
    __syncthreads();

    int pbase, br2, kbase;
    pair_chunk(b0, d1, d2, pbase, br2, kbase);
    float2 u[16];
    #pragma unroll
    for (int q = 0; q < 16; ++q) {
        int qp = (16 - q - br2) & 15;     // runtime addr, static reg index
        u[q] = zs[SWZ(pbase + qp)];
    }
    __syncthreads();   // all partner reads done before in-place overwrite

    const float4* ts4 = tspecU + (size_t)dp * TSLOT;
    #pragma unroll
    for (int q = 0; q < 16; ++q) {
        int k = kbase + (q << 9);
        bool lo = (q < 8) || (k <= 4096);
        int kr = lo ? k : 8192 - k;
        float2 z1 = lo ? v[q] : u[q];
        float2 z2 = lo ? u[q] : v[q];
        float4 T = ts4[kr];
        float x0r = 0.5f*(z1.x + z2.x), x0i = 0.5f*(z1.y - z2.y);
        float x1r = 0.5f*(z1.y + z2.y), x1i = 0.5f*(z2.x - z1.x);
        float y0r = x0r*T.x - x0i*T.y, y0i = x0r*T.y + x0i*T.x;
        float y1r = x1r*T.z - x1i*T.w, y1i = x1r*T.w + x1i*T.z;
        v[q] = lo ? make_float2(y0r - y1i, y0i + y1r)
                  : make_float2(y0r + y1i, y1r - y0i);
    }
    dft16<true>(v);
    #pragma unroll
    for (int q = 0; q < 16; ++q) zs[SWZ(i0 + q)] = v[q];
    __syncthreads();

    pass16mid<true>(zs, wt, t);
    __syncthreads();

    // ---- F: P256(inv) in regs + final radix-2 merge + store (n<4096 only) ----
    #pragma unroll
    for (int q = 0; q < 16; ++q) v[q] = zs[SWZ((blk<<12) + j + (q<<8))];
    twiddle_inv(v, wt, 2*j);
    dft16<true>(v);
    if (blk == 1) {
        #pragma unroll
        for (int q = 0; q < 16; ++q) zs[SWZ((1<<12) + j + (q<<8))] = v[q];
    }
    __syncthreads();
    if (blk == 0) {
        const float sc = 1.0f / (float)NFFT;
        #pragma unroll
        for (int q = 0; q < 16; ++q) {
            int n = j + (q << 8);
            float2 bb = zs[SWZ((1<<12) + n)];
            float2 r = cadd(v[q], cmulc(bb, wt[n]));
            r = make_float2(r.x * sc, r.y * sc);
            if (PACKED) slab[n] = r;
            else *(float2*)(outg + (size_t)b * NSEQ * D + (size_t)n * D + 2 * dp) = r;
        }
    }
}

// ---------- transpose/pack: (b,n,d) f32 -> (dp, b, n) float2 ----------
__global__ __launch_bounds__(256) void pack_kernel(const float* __restrict__ in,
                                                   float2* __restrict__ outp,
                                                   int Nrows, int Bsz) {
    __shared__ float tile[64][65];
    int tid = threadIdx.x;
    int n0 = blockIdx.x * 64;
    int d0 = blockIdx.y * 64;
    int b  = blockIdx.z;
    const float* ib = in + (size_t)b * Nrows * D;
    #pragma unroll
    for (int it = 0; it < 16; ++it) {
        int n_l = it * 4 + (tid >> 6);
        int d_l = tid & 63;
        tile[n_l][d_l] = ib[(size_t)(n0 + n_l) * D + d0 + d_l];
    }
    __syncthreads();
    #pragma unroll
    for (int it = 0; it < 8; ++it) {
        int flat = it * 256 + tid;
        int dp_l = flat >> 6;
        int n_l  = flat & 63;
        float2 v = make_float2(tile[n_l][2*dp_l], tile[n_l][2*dp_l + 1]);
        outp[((size_t)(d0/2 + dp_l) * Bsz + b) * (size_t)Nrows + n0 + n_l] = v;
    }
}

// ---------- unpack: (dp, b, n) float2 -> (b,n,d) f32 ----------
__global__ __launch_bounds__(256) void unpack_kernel(const float2* __restrict__ in,
                                                     float* __restrict__ outp) {
    __shared__ float tile[64][65];
    int tid = threadIdx.x;
    int n0 = blockIdx.x * 64;
    int d0 = blockIdx.y * 64;
    int b  = blockIdx.z;
    #pragma unroll
    for (int it = 0; it < 8; ++it) {
        int flat = it * 256 + tid;
        int dp_l = flat >> 6;
        int n_l  = flat & 63;
        float2 v = in[((size_t)(d0/2 + dp_l) * BATCH + b) * (size_t)NSEQ + n0 + n_l];
        tile[n_l][2*dp_l]     = v.x;
        tile[n_l][2*dp_l + 1] = v.y;
    }
    __syncthreads();
    float* ob = outp + (size_t)b * NSEQ * D;
    #pragma unroll
    for (int it = 0; it < 16; ++it) {
        int n_l = it * 4 + (tid >> 6);
        int d_l = tid & 63;
        ob[(size_t)(n0 + n_l) * D + d0 + d_l] = tile[n_l][d_l];
    }
}

extern "C" void kernel_launch(void* const* d_in, const int* in_sizes, int n_in,
                              void* d_out, int out_size, void* d_ws, size_t ws_size,
                              hipStream_t stream) {
    const float* x = (const float*)d_in[0];   // (4, 4096, 1024)
    const float* t = (const float*)d_in[1];   // (8192, 1024)
    float* outp = (float*)d_out;              // (4, 4096, 1024)

    char* ws = (char*)d_ws;
    float2* wtab   = (float2*)ws;                                   // 32 KB used, 64 KB reserved
    float4* tspecU = (float4*)(ws + 65536);                         // 512*4097*16 = 33,562,624
    const size_t OFF_REGION = 65536 + (size_t)NDP * TSLOT * 16;     // 33,628,160
    float2* region = (float2*)(ws + OFF_REGION);                    // tP (32 MB) then xP (64 MB)
    const size_t need_full = OFF_REGION + (size_t)NDP * BATCH * NSEQ * sizeof(float2);

    wtab_init<<<16, 256, 0, stream>>>(wtab);

    if (ws_size >= need_full) {
        pack_kernel<<<dim3(128, 16, 1), 256, 0, stream>>>(t, region, NFFT, 1);
        tspec_kernel<1><<<NDP, NT, 0, stream>>>(region, nullptr, wtab, tspecU);
        pack_kernel<<<dim3(64, 16, BATCH), 256, 0, stream>>>(x, region, NSEQ, BATCH);
        conv_kernel<1><<<dim3(NDP, BATCH, 1), NT, 0, stream>>>(region, nullptr, nullptr, wtab, tspecU);
        unpack_kernel<<<dim3(64, 16, BATCH), 256, 0, stream>>>(region, outp);
    } else {
        tspec_kernel<0><<<NDP, NT, 0, stream>>>(nullptr, t, wtab, tspecU);
        conv_kernel<0><<<dim3(NDP, BATCH, 1), NT, 0, stream>>>(nullptr, x, outp, wtab, tspecU);
    }
}

// Round 10
// 193.484 us; speedup vs baseline: 1.0759x; 1.0759x over previous
//
#include <hip/hip_runtime.h>
#include <hip/hip_bf16.h>

#define NFFT 8192
#define NH   4096
#define D    1024
#define NSEQ 4096
#define NDP  512
#define BATCH 4
#define NT   512
#define TSLOT 4097
#define PI_D 3.14159265358979323846

// 16-pt DFT internal constants
#define C1 0.92387953251128675613f
#define S1 0.38268343236508977173f
#define RT 0.70710678118654752440f

__device__ __forceinline__ int SWZ(int i) { return i ^ ((i >> 4) & 15) ^ ((i >> 8) & 15); }

__device__ __forceinline__ float2 cadd(float2 a, float2 b){ return make_float2(a.x+b.x, a.y+b.y); }
__device__ __forceinline__ float2 csub(float2 a, float2 b){ return make_float2(a.x-b.x, a.y-b.y); }
__device__ __forceinline__ float2 cmul(float2 a, float2 w){ return make_float2(a.x*w.x - a.y*w.y, a.x*w.y + a.y*w.x); }
__device__ __forceinline__ float2 cmulc(float2 a, float2 w){ return make_float2(a.x*w.x + a.y*w.y, a.y*w.x - a.x*w.y); }

// digit-reversal for radices [2,16,16,16] DIF (radix-2 first, stride 4096)
__device__ __forceinline__ int drev16(int k) {
    return ((k & 1) << 12) | (((k >> 1) & 15) << 8) | (((k >> 5) & 15) << 4) | ((k >> 9) & 15);
}
// bank-aware bijection tid(9b) x it(3b) -> k in [0,4096)
__device__ __forceinline__ int kmap16(int tid, int it) {
    return ((tid >> 7) & 3) | (it << 2) | ((tid & 15) << 5) | (((tid >> 4) & 7) << 9);
}

__global__ __launch_bounds__(256) void wtab_init(float2* __restrict__ wtab) {
    int m = blockIdx.x * 256 + threadIdx.x;   // grid 16 -> 4096 entries
    double a = -2.0 * PI_D * (double)m / (double)NFFT;
    wtab[m] = make_float2((float)cos(a), (float)sin(a));
}

// One radix-16 pass over LDS. Thread owns 16 points at stride H within its group.
template<int H, bool TW, bool INV>
__device__ __forceinline__ void pass16(float2* zs, const float2* __restrict__ wt, int t) {
    int blk = t >> 8;
    int i0, tw1i;
    if (H == 256)      { int j = t & 255;                      i0 = blk*4096 + j;           tw1i = 2*j;  }
    else if (H == 16)  { int g = (t>>4) & 15; int j = t & 15;  i0 = blk*4096 + g*256 + j;   tw1i = 32*j; }
    else               { int g = t & 255;                      i0 = blk*4096 + g*16;        tw1i = 0;    }

    float2 w1, w2, w3, w4, w8, w12;
    if (TW) {
        w1 = wt[tw1i];
        w2 = cmul(w1, w1);  w3 = cmul(w2, w1);
        w4 = cmul(w2, w2);  w8 = cmul(w4, w4);  w12 = cmul(w8, w4);
    }

    float2 v[16];
    #pragma unroll
    for (int q = 0; q < 16; ++q) v[q] = zs[SWZ(i0 + H*q)];

    if (INV && TW) {
        v[1]=cmulc(v[1],w1);  v[2]=cmulc(v[2],w2);  v[3]=cmulc(v[3],w3);
        v[4]=cmulc(v[4],w4);  v[5]=cmulc(v[5],cmul(w4,w1));  v[6]=cmulc(v[6],cmul(w4,w2));  v[7]=cmulc(v[7],cmul(w4,w3));
        v[8]=cmulc(v[8],w8);  v[9]=cmulc(v[9],cmul(w8,w1));  v[10]=cmulc(v[10],cmul(w8,w2)); v[11]=cmulc(v[11],cmul(w8,w3));
        v[12]=cmulc(v[12],w12); v[13]=cmulc(v[13],cmul(w12,w1)); v[14]=cmulc(v[14],cmul(w12,w2)); v[15]=cmulc(v[15],cmul(w12,w3));
    }

    // layer 1
    float2 s[4][4];
    #pragma unroll
    for (int i = 0; i < 4; ++i) {
        float2 z0=v[i], z1=v[i+4], z2=v[i+8], z3=v[i+12];
        float2 A=cadd(z0,z2), Cc=csub(z0,z2), B=cadd(z1,z3), Dd=csub(z1,z3);
        s[i][0] = cadd(A,B);
        s[i][2] = csub(A,B);
        if (!INV) { s[i][1] = make_float2(Cc.x+Dd.y, Cc.y-Dd.x);
                    s[i][3] = make_float2(Cc.x-Dd.y, Cc.y+Dd.x); }
        else      { s[i][1] = make_float2(Cc.x-Dd.y, Cc.y+Dd.x);
                    s[i][3] = make_float2(Cc.x+Dd.y, Cc.y-Dd.x); }
    }
    // internal twiddles W16^{i*o} (conj for INV)
    if (!INV) {
        s[1][1]=cmul(s[1][1],make_float2(C1,-S1)); s[1][2]=cmul(s[1][2],make_float2(RT,-RT)); s[1][3]=cmul(s[1][3],make_float2(S1,-C1));
        s[2][1]=cmul(s[2][1],make_float2(RT,-RT)); s[2][2]=make_float2(s[2][2].y,-s[2][2].x); s[2][3]=cmul(s[2][3],make_float2(-RT,-RT));
        s[3][1]=cmul(s[3][1],make_float2(S1,-C1)); s[3][2]=cmul(s[3][2],make_float2(-RT,-RT)); s[3][3]=cmul(s[3][3],make_float2(-C1,S1));
    } else {
        s[1][1]=cmul(s[1][1],make_float2(C1,S1));  s[1][2]=cmul(s[1][2],make_float2(RT,RT));  s[1][3]=cmul(s[1][3],make_float2(S1,C1));
        s[2][1]=cmul(s[2][1],make_float2(RT,RT));  s[2][2]=make_float2(-s[2][2].y,s[2][2].x); s[2][3]=cmul(s[2][3],make_float2(-RT,RT));
        s[3][1]=cmul(s[3][1],make_float2(S1,C1));  s[3][2]=cmul(s[3][2],make_float2(-RT,RT)); s[3][3]=cmul(s[3][3],make_float2(-C1,-S1));
    }
    // layer 2
    float2 y[16];
    #pragma unroll
    for (int o = 0; o < 4; ++o) {
        float2 z0=s[0][o], z1=s[1][o], z2=s[2][o], z3=s[3][o];
        float2 A=cadd(z0,z2), Cc=csub(z0,z2), B=cadd(z1,z3), Dd=csub(z1,z3);
        y[o]    = cadd(A,B);
        y[o+8]  = csub(A,B);
        if (!INV) { y[o+4]  = make_float2(Cc.x+Dd.y, Cc.y-Dd.x);
                    y[o+12] = make_float2(Cc.x-Dd.y, Cc.y+Dd.x); }
        else      { y[o+4]  = make_float2(Cc.x-Dd.y, Cc.y+Dd.x);
                    y[o+12] = make_float2(Cc.x+Dd.y, Cc.y-Dd.x); }
    }

    if (!INV && TW) {
        y[1]=cmul(y[1],w1);  y[2]=cmul(y[2],w2);  y[3]=cmul(y[3],w3);
        y[4]=cmul(y[4],w4);  y[5]=cmul(y[5],cmul(w4,w1));  y[6]=cmul(y[6],cmul(w4,w2));  y[7]=cmul(y[7],cmul(w4,w3));
        y[8]=cmul(y[8],w8);  y[9]=cmul(y[9],cmul(w8,w1));  y[10]=cmul(y[10],cmul(w8,w2)); y[11]=cmul(y[11],cmul(w8,w3));
        y[12]=cmul(y[12],w12); y[13]=cmul(y[13],cmul(w12,w1)); y[14]=cmul(y[14],cmul(w12,w2)); y[15]=cmul(y[15],cmul(w12,w3));
    }
    #pragma unroll
    for (int r = 0; r < 16; ++r) zs[SWZ(i0 + H*r)] = y[r];
}

// ---------- tspec: strided t read, fwd FFT, untangle -> slot-ordered (T0,T1) ----------
// grid 512, 1D. XCD swizzle: xcd = wg&7 owns dp in [xcd*64, xcd*64+64) so the 8
// blocks sharing each 64B t-line sit on one XCD's L2.
__global__ __launch_bounds__(NT, 2) void tspec_kernel(const float* __restrict__ tg,
                                                      const float2* __restrict__ wt,
                                                      float4* __restrict__ tspecU) {
    __shared__ float2 zs[NFFT];
    int wg = blockIdx.x;
    int dp = ((wg & 7) << 6) | (wg >> 3);   // bijective [0,512)
    int t  = threadIdx.x;

    const float* tb = tg + 2 * dp;
    #pragma unroll
    for (int it = 0; it < 8; ++it) {
        int idx = t + it * NT;
        float2 v0 = *(const float2*)(tb + (size_t)idx * D);
        float2 v1 = *(const float2*)(tb + (size_t)(idx + NH) * D);
        zs[SWZ(idx)]      = cadd(v0, v1);
        zs[SWZ(idx + NH)] = cmul(csub(v0, v1), wt[idx]);
    }
    __syncthreads();
    pass16<256, true,  false>(zs, wt, t); __syncthreads();
    pass16<16,  true,  false>(zs, wt, t); __syncthreads();
    pass16<1,   false, false>(zs, wt, t); __syncthreads();

    float4* o = tspecU + (size_t)dp * TSLOT;
    #pragma unroll
    for (int it = 0; it < 8; ++it) {
        int k  = kmap16(t, it);
        int p1 = drev16(k);
        int p2 = drev16((NFFT - k) & (NFFT - 1));
        float2 z1 = zs[SWZ(p1)], z2 = zs[SWZ(p2)];
        o[it * NT + t] = make_float4(0.5f*(z1.x + z2.x), 0.5f*(z1.y - z2.y),
                                     0.5f*(z1.y + z2.y), 0.5f*(z2.x - z1.x));
    }
    if (t == 0) {   // Nyquist bin k=4096 at position drev16(4096)=8
        float2 zn = zs[SWZ(8)];
        o[4096] = make_float4(zn.x, 0.f, zn.y, 0.f);
    }
}

// ---------- conv: grid 2048, 1D. Strided x read / out write, XCD-local line sharing ----------
// wg -> (xcd = wg&7, ix = wg>>3); b = ix>>6 (b-generations sequential per XCD so the
// 2MB per-b x-footprint fits the 4MB per-XCD L2); dp = xcd*64 + (ix&63).
__global__ __launch_bounds__(NT, 2) void conv_kernel(const float* __restrict__ xg,
                                                     float* __restrict__ outg,
                                                     const float2* __restrict__ wt,
                                                     const float4* __restrict__ tspecU) {
    __shared__ float2 zs[NFFT];
    int wg = blockIdx.x;
    int xcd = wg & 7, ix = wg >> 3;
    int b  = ix >> 6;
    int dp = (xcd << 6) | (ix & 63);
    int t  = threadIdx.x;

    const float* xb = xg + (size_t)b * NSEQ * D + 2 * dp;
    // load + fused first radix-2 (upper half is zero padding)
    #pragma unroll
    for (int it = 0; it < 8; ++it) {
        int idx = t + it * NT;
        float2 v = *(const float2*)(xb + (size_t)idx * D);
        zs[SWZ(idx)]      = v;                     // x + 0
        zs[SWZ(idx + NH)] = cmul(v, wt[idx]);      // (x - 0)*W^idx
    }
    __syncthreads();
    pass16<256, true,  false>(zs, wt, t); __syncthreads();
    pass16<16,  true,  false>(zs, wt, t); __syncthreads();
    pass16<1,   false, false>(zs, wt, t); __syncthreads();

    // untangle * multiply * repack (T streamed from slot-ordered tspecU, coalesced)
    const float4* ts4 = tspecU + (size_t)dp * TSLOT;
    #pragma unroll
    for (int it = 0; it < 8; ++it) {
        int k  = kmap16(t, it);
        int p1 = drev16(k);
        int p2 = drev16((NFFT - k) & (NFFT - 1));
        float2 z1 = zs[SWZ(p1)], z2 = zs[SWZ(p2)];
        float4 T  = ts4[it * NT + t];
        float x0r = 0.5f*(z1.x + z2.x), x0i = 0.5f*(z1.y - z2.y);
        float x1r = 0.5f*(z1.y + z2.y), x1i = 0.5f*(z2.x - z1.x);
        float y0r = x0r*T.x - x0i*T.y, y0i = x0r*T.y + x0i*T.x;
        float y1r = x1r*T.z - x1i*T.w, y1i = x1r*T.w + x1i*T.z;
        zs[SWZ(p1)] = make_float2(y0r - y1i, y0i + y1r);
        zs[SWZ(p2)] = make_float2(y0r + y1i, y1r - y0i);
    }
    if (t == 0) {
        float4 T = ts4[4096];
        float2 zn = zs[SWZ(8)];
        zs[SWZ(8)] = make_float2(zn.x * T.x, zn.y * T.z);
    }
    __syncthreads();

    pass16<1,   false, true>(zs, wt, t); __syncthreads();
    pass16<16,  true,  true>(zs, wt, t); __syncthreads();
    pass16<256, true,  true>(zs, wt, t); __syncthreads();

    // final radix-2 (only n < 4096 needed) fused with strided store
    const float sc = 1.0f / (float)NFFT;
    float* ob = outg + (size_t)b * NSEQ * D + 2 * dp;
    #pragma unroll
    for (int it = 0; it < 8; ++it) {
        int n = t + it * NT;
        float2 a  = zs[SWZ(n)];
        float2 bb = zs[SWZ(n + NH)];
        float2 r  = cadd(a, cmulc(bb, wt[n]));
        *(float2*)(ob + (size_t)n * D) = make_float2(r.x * sc, r.y * sc);
    }
}

extern "C" void kernel_launch(void* const* d_in, const int* in_sizes, int n_in,
                              void* d_out, int out_size, void* d_ws, size_t ws_size,
                              hipStream_t stream) {
    const float* x = (const float*)d_in[0];   // (4, 4096, 1024) f32
    const float* t = (const float*)d_in[1];   // (8192, 1024) f32
    float* outp = (float*)d_out;              // (4, 4096, 1024) f32

    char* ws = (char*)d_ws;
    float2* wtab   = (float2*)ws;                    // 32 KB used, 64 KB reserved
    float4* tspecU = (float4*)(ws + 65536);          // 512*4097*16 = 33,562,624 B (ws >= 33.7MB proven)

    wtab_init<<<16, 256, 0, stream>>>(wtab);
    tspec_kernel<<<NDP, NT, 0, stream>>>(t, wtab, tspecU);
    conv_kernel<<<NDP * BATCH, NT, 0, stream>>>(x, outp, wtab, tspecU);
}